// Round 4
// baseline (256.481 us; speedup 1.0000x reference)
//
#include <hip/hip_runtime.h>
#include <stdint.h>

#define T 4096
#define E 64
#define NBH 32
#define NWIN 32                 // T / 128 windows

typedef __attribute__((ext_vector_type(8))) short short8;
typedef __attribute__((ext_vector_type(4))) float f32x4;

__device__ __forceinline__ short f2bf(float x) {
  unsigned u = __float_as_uint(x);
  u += 0x7fffu + ((u >> 16) & 1u);   // RNE
  return (short)(u >> 16);
}

__device__ __forceinline__ unsigned cvtpk(float lo, float hi) {
  unsigned r;
  asm("v_cvt_pk_bf16_f32 %0, %1, %2" : "=v"(r) : "v"(lo), "v"(hi));
  return r;
}

__device__ __forceinline__ short8 pack8(float4 f0, float4 f1) {
  union { unsigned u[4]; short8 s8; } r;
  r.u[0] = cvtpk(f0.x, f0.y); r.u[1] = cvtpk(f0.z, f0.w);
  r.u[2] = cvtpk(f1.x, f1.y); r.u[3] = cvtpk(f1.z, f1.w);
  return r.s8;
}

__device__ __forceinline__ short8 pack8s(float4 f0, float4 f1, float s) {
  union { unsigned u[4]; short8 s8; } r;
  r.u[0] = cvtpk(f0.x*s, f0.y*s); r.u[1] = cvtpk(f0.z*s, f0.w*s);
  r.u[2] = cvtpk(f1.x*s, f1.y*s); r.u[3] = cvtpk(f1.z*s, f1.w*s);
  return r.s8;
}

// ---- pass 1: V[bh][t][e] f32  ->  Vt[bh][e][t] bf16 (LDS-tiled transpose) ----
__global__ __launch_bounds__(256)
void v_transpose(const float* __restrict__ vg, short* __restrict__ vt) {
  __shared__ float tile[64][65];            // +1 pad: column reads conflict-free
  const int bh = blockIdx.y;
  const int t0 = blockIdx.x * 64;
  const int tid = threadIdx.x;
  const int c = tid & 63, r4 = tid >> 6;
  const float* src = vg + ((size_t)bh * T + t0) * E;
#pragma unroll
  for (int i = 0; i < 16; ++i) {
    int r = i * 4 + r4;
    tile[r][c] = src[(size_t)r * E + c];    // coalesced 256B row reads
  }
  __syncthreads();
  short* dst = vt + (size_t)bh * E * T + t0;
#pragma unroll
  for (int i = 0; i < 16; ++i) {
    int e = i * 4 + r4;
    dst[(size_t)e * T + c] = f2bf(tile[c][e]);   // coalesced 128B bf16 writes
  }
}

// ---- butterfly (verified in round 3): redistribute in-register P^T pairs into
//      the PV B-fragment for keys KT*32 + lg*8 .. +8 ----
template<int KT>
__device__ __forceinline__ short8 pv_bfrag(const unsigned* W0, const unsigned* W1, int lg) {
  const bool lowhalf = (lg < 2);
  const bool sendR = (lg == 0) | (lg == 3);
  const int cA = KT * 2, cB = cA + 1;
  unsigned P0 = lowhalf ? W0[cB] : W0[cA];
  unsigned P1 = lowhalf ? W1[cB] : W1[cA];
  unsigned R0 = __shfl_xor(P0, 32);
  unsigned R1 = __shfl_xor(P1, 32);
  unsigned L0 = lowhalf ? W0[cA] : W0[cB];
  unsigned L1 = lowhalf ? W1[cA] : W1[cB];
  unsigned S0 = sendR ? R0 : L0;
  unsigned S1 = sendR ? R1 : L1;
  unsigned T0 = __shfl_xor(S0, 16);
  unsigned T1 = __shfl_xor(S1, 16);
  unsigned F0 = (lg == 0) ? L0 : ((lg == 2) ? R0 : T0);
  unsigned F1 = (lg == 0) ? L1 : ((lg == 2) ? R1 : T1);
  unsigned G0 = (lg == 1) ? R0 : ((lg == 3) ? L0 : T0);
  unsigned G1 = (lg == 1) ? R1 : ((lg == 3) ? L1 : T1);
  union { unsigned u[4]; short8 s; } bu;
  bu.u[0] = F0; bu.u[1] = F1; bu.u[2] = G0; bu.u[3] = G1;
  return bu.s;
}

// ---- pass 2: attention. One block per (window, bh); 4 waves x 32 q-rows.
// NO LDS, NO BARRIERS: every wave runs its window independently. K/Kr fragments
// loaded per-wave from global f32 (L1/L2-absorbed 4x redundancy, halved by the
// 2-q-tile waves: each K/V fragment feeds 2 MFMAs). V from the bf16 transposed
// tensor (contiguous 16B fragment loads). Swapped-operand S^T = mfma(K,Q) with
// in-register softmax + butterfly P redistribution (verified round 3).
__global__ __launch_bounds__(256)
void la_attn(const float* __restrict__ qg, const float* __restrict__ kg,
             const float* __restrict__ qrg, const float* __restrict__ krg,
             const short* __restrict__ vtg, float* __restrict__ outg) {
  // XCD-aware swizzle: adjacent windows (shared K/V) on one XCD's L2
  const int lid = blockIdx.y * NWIN + blockIdx.x;
  const int wl  = (lid & 7) * 128 + (lid >> 3);
  const int win = wl & (NWIN - 1), bh = wl >> 5;

  const int tid = threadIdx.x;
  const int wv = tid >> 6, lane = tid & 63;
  const int li = lane & 15, lg = lane >> 4;
  const size_t rbase = (size_t)bh * T;
  const int qb = wv * 32;                       // wave's q base (2 tiles of 16)

  // ---- Q fragments: 2 q-tiles x 4 kt (scaled by 1/sqrt(64)) ----
  short8 aF[2][4];
#pragma unroll
  for (int qt = 0; qt < 2; ++qt) {
    const size_t qrow = rbase + (size_t)win * 128 + qb + qt * 16 + li;
#pragma unroll
    for (int kt = 0; kt < 4; ++kt) {
      const float* sp = (kt < 2 ? qg : qrg) + qrow * E + (kt & 1) * 32 + lg * 8;
      float4 f0 = *(const float4*)sp, f1 = *(const float4*)(sp + 4);
      aF[qt][kt] = pack8s(f0, f1, 0.125f);
    }
  }

  float m[2] = {-1e30f, -1e30f}, l[2] = {0.f, 0.f};
  f32x4 O[2][4];
#pragma unroll
  for (int qt = 0; qt < 2; ++qt)
#pragma unroll
    for (int nt = 0; nt < 4; ++nt) O[qt][nt] = f32x4{0.f, 0.f, 0.f, 0.f};

  const int s0 = (win == 0) ? 2 : 0;            // skip padding sub-tiles

  for (int s = s0; s < 4; ++s) {
    const int tloc = win * 128 + (s - 2) * 64;  // key base (>=0 for s>=s0)
    const size_t keyb = rbase + tloc;

    // ---- S^T = mfma(K, Q): per ct load K/Kr rows f32, cvt, 8 MFMAs ----
    f32x4 p[2][4];
#pragma unroll
    for (int qt = 0; qt < 2; ++qt)
#pragma unroll
      for (int ct = 0; ct < 4; ++ct) p[qt][ct] = f32x4{0.f, 0.f, 0.f, 0.f};
#pragma unroll
    for (int ct = 0; ct < 4; ++ct) {
      const float* rk = kg  + (keyb + ct * 16 + li) * E + lg * 8;
      const float* rr = krg + (keyb + ct * 16 + li) * E + lg * 8;
      float4 a0 = *(const float4*)(rk);      float4 a1 = *(const float4*)(rk + 4);
      float4 b0 = *(const float4*)(rk + 32); float4 b1 = *(const float4*)(rk + 36);
      float4 c0 = *(const float4*)(rr);      float4 c1 = *(const float4*)(rr + 4);
      float4 d0 = *(const float4*)(rr + 32); float4 d1 = *(const float4*)(rr + 36);
      short8 kA0 = pack8(a0, a1), kA1 = pack8(b0, b1);
      short8 kA2 = pack8(c0, c1), kA3 = pack8(d0, d1);
#pragma unroll
      for (int qt = 0; qt < 2; ++qt) {
        p[qt][ct] = __builtin_amdgcn_mfma_f32_16x16x32_bf16(kA0, aF[qt][0], p[qt][ct], 0, 0, 0);
        p[qt][ct] = __builtin_amdgcn_mfma_f32_16x16x32_bf16(kA1, aF[qt][1], p[qt][ct], 0, 0, 0);
        p[qt][ct] = __builtin_amdgcn_mfma_f32_16x16x32_bf16(kA2, aF[qt][2], p[qt][ct], 0, 0, 0);
        p[qt][ct] = __builtin_amdgcn_mfma_f32_16x16x32_bf16(kA3, aF[qt][3], p[qt][ct], 0, 0, 0);
      }
    }

    // ---- V^T fragments (bf16, contiguous 16B): issue before softmax ----
    short8 vA[2][4];
#pragma unroll
    for (int kt = 0; kt < 2; ++kt)
#pragma unroll
      for (int nt = 0; nt < 4; ++nt)
        vA[kt][nt] = *(const short8*)(vtg + ((size_t)bh * E + nt * 16 + li) * T
                                          + tloc + kt * 32 + lg * 8);

    // ---- per q-tile: causal mask, online softmax, pack, butterfly, PV ----
#pragma unroll
    for (int qt = 0; qt < 2; ++qt) {
      const int q_i = qb + qt * 16 + li;        // window-local q row
      if (s >= 2) {
        const int joff = (s - 2) * 64 + lg * 4;
#pragma unroll
        for (int ct = 0; ct < 4; ++ct)
#pragma unroll
          for (int r = 0; r < 4; ++r)
            if (joff + ct * 16 + r > q_i) p[qt][ct][r] = -1e30f;
      }
      float mx = -1e30f;
#pragma unroll
      for (int ct = 0; ct < 4; ++ct)
#pragma unroll
        for (int r = 0; r < 4; ++r) mx = fmaxf(mx, p[qt][ct][r]);
      mx = fmaxf(mx, __shfl_xor(mx, 16));
      mx = fmaxf(mx, __shfl_xor(mx, 32));
      const float mn = fmaxf(m[qt], mx);
      const float f = __expf(m[qt] - mn);       // first sub: exp(-huge) -> 0
      float sm = 0.f;
#pragma unroll
      for (int ct = 0; ct < 4; ++ct)
#pragma unroll
        for (int r = 0; r < 4; ++r) {
          float e = __expf(p[qt][ct][r] - mn);
          p[qt][ct][r] = e;
          sm += e;
        }
      sm += __shfl_xor(sm, 16);
      sm += __shfl_xor(sm, 32);
      l[qt] = l[qt] * f + sm;
      m[qt] = mn;
#pragma unroll
      for (int nt = 0; nt < 4; ++nt)
#pragma unroll
        for (int r = 0; r < 4; ++r) O[qt][nt][r] *= f;

      unsigned W0[4], W1[4];
#pragma unroll
      for (int ct = 0; ct < 4; ++ct) {
        W0[ct] = cvtpk(p[qt][ct][0], p[qt][ct][1]);
        W1[ct] = cvtpk(p[qt][ct][2], p[qt][ct][3]);
      }
      {
        const short8 bP0 = pv_bfrag<0>(W0, W1, lg);
#pragma unroll
        for (int nt = 0; nt < 4; ++nt)
          O[qt][nt] = __builtin_amdgcn_mfma_f32_16x16x32_bf16(vA[0][nt], bP0, O[qt][nt], 0, 0, 0);
      }
      {
        const short8 bP1 = pv_bfrag<1>(W0, W1, lg);
#pragma unroll
        for (int nt = 0; nt < 4; ++nt)
          O[qt][nt] = __builtin_amdgcn_mfma_f32_16x16x32_bf16(vA[1][nt], bP1, O[qt][nt], 0, 0, 0);
      }
    }
  }

  // ---- epilogue: normalize, store O^T (lane: q=li, e=nt*16+lg*4+{0..3}) ----
#pragma unroll
  for (int qt = 0; qt < 2; ++qt) {
    const float linv = 1.f / l[qt];
    float* op = outg + (rbase + (size_t)win * 128 + qb + qt * 16 + li) * E + lg * 4;
#pragma unroll
    for (int nt = 0; nt < 4; ++nt) {
      float4 o = { O[qt][nt][0] * linv, O[qt][nt][1] * linv,
                   O[qt][nt][2] * linv, O[qt][nt][3] * linv };
      *(float4*)(op + nt * 16) = o;
    }
  }
}

extern "C" void kernel_launch(void* const* d_in, const int* in_sizes, int n_in,
                              void* d_out, int out_size, void* d_ws, size_t ws_size,
                              hipStream_t stream) {
  const float* q  = (const float*)d_in[0];
  const float* k  = (const float*)d_in[1];
  const float* qr = (const float*)d_in[2];
  const float* kr = (const float*)d_in[3];
  const float* v  = (const float*)d_in[4];
  float* out = (float*)d_out;
  short* vt = (short*)d_ws;                        // 32*64*4096*2 B = 16.8 MB
  v_transpose<<<dim3(T / 64, NBH), 256, 0, stream>>>(v, vt);
  la_attn<<<dim3(NWIN, NBH), 256, 0, stream>>>(q, k, qr, kr, vt, out);
}